// Round 10
// baseline (352.061 us; speedup 1.0000x reference)
//
#include <hip/hip_runtime.h>
#include <cstdint>

typedef unsigned short u16;
typedef __attribute__((ext_vector_type(8))) short bf16x8;
typedef __attribute__((ext_vector_type(4))) float f32x4;

__device__ __forceinline__ u16 f2b(float x) {
  unsigned u = __float_as_uint(x);
  u += 0x7FFFu + ((u >> 16) & 1u);
  return (u16)(u >> 16);
}

__device__ __forceinline__ void gload16(const void* g, void* l) {
  __builtin_amdgcn_global_load_lds(
      (const __attribute__((address_space(1))) void*)g,
      (__attribute__((address_space(3))) void*)l, 16, 0, 0);
}

template <int N>
__device__ __forceinline__ void vmwait() {
  if constexpr (N == 0) asm volatile("s_waitcnt vmcnt(0)" ::: "memory");
  else if constexpr (N == 4) asm volatile("s_waitcnt vmcnt(4)" ::: "memory");
  else if constexpr (N == 8) asm volatile("s_waitcnt vmcnt(8)" ::: "memory");
}

// ---------------------------------------------------------------------------
// 128x32 bf16 slice stored as 64 virtual rows of 64 u16 (128 B), 8 chunks of
// 16 B each; chunk XOR'd with (vrow&7) — the exact pattern measured at ZERO
// bank conflicts in rounds 5-8 (128 B spans all 32 banks once; XOR spreads a
// chunk-column over all 8 chunk positions). Both-sides rule (m231): LDS dest
// linear, global source inverse-swizzled, read swizzled with the same
// involution.   r = vrow*2 + (chunk>=4), col-chunk = chunk&3.
// ---------------------------------------------------------------------------
__device__ __forceinline__ void stage128(const u16* __restrict__ G,
                                         long long ld, int kb,
                                         u16* Ldst, int tid) {
#pragma unroll
  for (int j = 0; j < 2; ++j) {
    const int P = j * 256 + tid;
    const int vr = P >> 3;
    const int ch = (P & 7) ^ (vr & 7);
    const int r = vr * 2 + (ch >> 2), c = ch & 3;
    gload16(G + (long long)r * ld + kb + c * 8, Ldst + P * 8);
  }
}

__device__ __forceinline__ bf16x8 fr4(const u16* R, int row, int chunk) {
  const int vr = row >> 1;
  const int ch = (((row & 1) << 2) | chunk) ^ (vr & 7);
  return *(const bf16x8*)(R + vr * 64 + ch * 8);
}

// ---------------------------------------------------------------------------
// e3p: multi-block deep-pipelined GEMM. C = A @ B^T.
// 128x128 tile, BK=32, 256 thr (4 waves 2x2, wave=64x64, 16 MFMA/iter),
// THREE 16KB LDS buffers (48KB -> 3 blocks/CU), stage issued 2 iterations
// ahead, counted vmcnt(4) at top of iter (never 0 mid-loop; m135 oldest-first
// semantics make stage(t) proven-landed while stage(t+1) stays in flight).
// DMA latency budget ~2 iterations >= HBM latency. One barrier per iter.
// EPI: 0=QKV split  1=theta->cat halves  2=bf16  3=f32+bias  4=f32 plain
// ---------------------------------------------------------------------------
template <int EPI>
__global__ __launch_bounds__(256, 3) void e3p(
    const u16* __restrict__ A, long long lda, long long sAz,
    const u16* __restrict__ B, long long ldb, long long sBz,
    void* __restrict__ C0, void* __restrict__ C1, void* __restrict__ C2,
    long long ldc, long long sCz, int K,
    const float* __restrict__ b0, const float* __restrict__ b1,
    const float* __restrict__ b2, float preScale, const float* __restrict__ esp) {
  constexpr int HALF = 4096;           // u16 per operand slice (128x32)
  constexpr int BUFU = 2 * HALF;       // 16KB per buffer
  __shared__ __align__(16) u16 lds[3 * BUFU];  // 48KB

  // XCD-aware bijective swizzle within the z-slice (S % 8 == 0 everywhere)
  const int gx = gridDim.x, S = gx * gridDim.y;
  const int hw = blockIdx.y * gx + blockIdx.x;
  const int l = (hw & 7) * (S >> 3) + (hw >> 3);
  const int bx = l % gx, by = l / gx;
  const int z = blockIdx.z;
  const long long tM = (long long)by * 128;
  const long long tN = (long long)bx * 128;
  const u16* GA = A + z * sAz + tM * lda;
  const u16* GB = B + z * sBz + tN * ldb;
  const int tid = threadIdx.x;
  const int NT = K >> 5;               // >= 32 here

  // prologue: stage tiles 0 and 1
  stage128(GA, lda, 0, lds, tid);
  stage128(GB, ldb, 0, lds + HALF, tid);
  stage128(GA, lda, 32, lds + BUFU, tid);
  stage128(GB, ldb, 32, lds + BUFU + HALF, tid);

  const int wid = tid >> 6, lane = tid & 63;
  const int wr = (wid >> 1) * 64, wc = (wid & 1) * 64;
  const int lr = lane & 15, cA = lane >> 4;
  f32x4 acc[4][4] = {};

  for (int t = 0; t < NT; ++t) {
    // tile t proven-landed; tile t+1's 4 loads stay in flight
    if (t < NT - 1) vmwait<4>(); else vmwait<0>();
    __builtin_amdgcn_s_barrier();      // + WAR seal for the stage below
    if (t + 2 < NT) {
      u16* nxt = lds + ((t + 2) % 3) * BUFU;
      stage128(GA, lda, (t + 2) * 32, nxt, tid);
      stage128(GB, ldb, (t + 2) * 32, nxt + HALF, tid);
    }
    const u16* cur = lds + (t % 3) * BUFU;
    bf16x8 a[4], b[4];
#pragma unroll
    for (int m = 0; m < 4; ++m) a[m] = fr4(cur, wr + m * 16 + lr, cA);
#pragma unroll
    for (int n = 0; n < 4; ++n) b[n] = fr4(cur + HALF, wc + n * 16 + lr, cA);
#pragma unroll
    for (int m = 0; m < 4; ++m)
#pragma unroll
      for (int n = 0; n < 4; ++n)
        acc[m][n] = __builtin_amdgcn_mfma_f32_16x16x32_bf16(a[m], b[n],
                                                            acc[m][n], 0, 0, 0);
  }

  // epilogue: C/D map col=lane&15, row=(lane>>4)*4+reg
  const int rr = (lane >> 4) << 2;
  float ps = preScale, mul = 1.0f;
  if constexpr (EPI == 1) {
    ps = (z == 0) ? preScale : 1.0f;
    mul = (z == 0) ? esp[0] : 1.0f;
  }
#pragma unroll
  for (int m = 0; m < 4; ++m) {
#pragma unroll
    for (int n = 0; n < 4; ++n) {
      const int col = (int)tN + wc + n * 16 + lr;
#pragma unroll
      for (int r = 0; r < 4; ++r) {
        const long long row = tM + wr + m * 16 + rr + r;
        const float v = acc[m][n][r];
        if constexpr (EPI == 0) {
          const int gg = col >> 10, cc = col & 1023;
          if (gg == 0)      ((u16*)C0)[row * 2048 + cc] = f2b((v + b0[cc]) * 0.03125f);
          else if (gg == 1) ((u16*)C1)[row * 2048 + cc] = f2b(v + b1[cc]);
          else              ((u16*)C2)[row * 1024 + cc] = f2b(v + b2[cc]);
        } else if constexpr (EPI == 1) {
          const float tt = v * ps + b0[col];
          const float sg = 1.f / (1.f + __expf(-tt));
          ((u16*)C0)[z * sCz + row * ldc + col] = f2b(mul * cospif(sg));
        } else if constexpr (EPI == 2) {
          ((u16*)C0)[z * sCz + row * ldc + col] = f2b(v);
        } else if constexpr (EPI == 3) {
          ((float*)C0)[z * sCz + row * ldc + col] = v + b0[col];
        } else {
          ((float*)C0)[z * sCz + row * ldc + col] = v;
        }
      }
    }
  }
}

// row softmax over [8192][2048]: fp32 in-place + bf16 copy
__global__ __launch_bounds__(256) void softmax_rows(float* __restrict__ L,
                                                    u16* __restrict__ AB) {
  const long long row = blockIdx.x;
  float4* p4 = (float4*)(L + row * 2048);
  const int tid = threadIdx.x;
  float4 a = p4[tid], b = p4[tid + 256];
  float m = fmaxf(fmaxf(fmaxf(a.x, a.y), fmaxf(a.z, a.w)),
                  fmaxf(fmaxf(b.x, b.y), fmaxf(b.z, b.w)));
#pragma unroll
  for (int o = 32; o > 0; o >>= 1) m = fmaxf(m, __shfl_xor(m, o));
  __shared__ float rmax[4], rsum[4];
  const int wid = tid >> 6, lane = tid & 63;
  if (lane == 0) rmax[wid] = m;
  __syncthreads();
  m = fmaxf(fmaxf(rmax[0], rmax[1]), fmaxf(rmax[2], rmax[3]));
  a.x = __expf(a.x - m); a.y = __expf(a.y - m);
  a.z = __expf(a.z - m); a.w = __expf(a.w - m);
  b.x = __expf(b.x - m); b.y = __expf(b.y - m);
  b.z = __expf(b.z - m); b.w = __expf(b.w - m);
  float s = a.x + a.y + a.z + a.w + b.x + b.y + b.z + b.w;
#pragma unroll
  for (int o = 32; o > 0; o >>= 1) s += __shfl_xor(s, o);
  if (lane == 0) rsum[wid] = s;
  __syncthreads();
  s = rsum[0] + rsum[1] + rsum[2] + rsum[3];
  const float inv = 1.0f / s;
  a.x *= inv; a.y *= inv; a.z *= inv; a.w *= inv;
  b.x *= inv; b.y *= inv; b.z *= inv; b.w *= inv;
  p4[tid] = a;
  p4[tid + 256] = b;
  ushort4* o4 = (ushort4*)(AB + row * 2048);
  o4[tid]       = make_ushort4(f2b(a.x), f2b(a.y), f2b(a.z), f2b(a.w));
  o4[tid + 256] = make_ushort4(f2b(b.x), f2b(b.y), f2b(b.z), f2b(b.w));
}

__global__ __launch_bounds__(256) void cvt_x(const float* __restrict__ X,
                                             u16* __restrict__ XB) {
  const int i = blockIdx.x * 256 + threadIdx.x;
  float4 v = ((const float4*)X)[i];
  ((ushort4*)XB)[i] = make_ushort4(f2b(v.x), f2b(v.y), f2b(v.z), f2b(v.w));
}

// transpose+convert 5 weight matrices [1024,1024] f32 -> bf16 W^T
__global__ void cvt_w(const float* __restrict__ W0, const float* __restrict__ W1,
                      const float* __restrict__ W2, const float* __restrict__ W3,
                      const float* __restrict__ W4, u16* __restrict__ WT) {
  __shared__ float t[32][33];
  const int z = blockIdx.z;
  const float* W = (z == 0) ? W0 : (z == 1) ? W1 : (z == 2) ? W2 : (z == 3) ? W3 : W4;
  u16* D = WT + (long long)z * 1024 * 1024;
  const int c0 = blockIdx.x * 32, r0 = blockIdx.y * 32;
  const int tx = threadIdx.x, ty = threadIdx.y;
#pragma unroll
  for (int i = 0; i < 4; ++i)
    t[ty + i * 8][tx] = W[(long long)(r0 + ty + i * 8) * 1024 + c0 + tx];
  __syncthreads();
#pragma unroll
  for (int i = 0; i < 4; ++i)
    D[(long long)(c0 + ty + i * 8) * 1024 + r0 + tx] = f2b(t[tx][ty + i * 8]);
}

// Vb [8192,1024] bf16 -> VT [4][1024,2048] bf16
__global__ void transpose_v(const u16* __restrict__ Vb, u16* __restrict__ VT) {
  __shared__ u16 t[32][33];
  const int b = blockIdx.z;
  const u16* V = Vb + (long long)b * 2048 * 1024;
  u16* O = VT + (long long)b * 1024 * 2048;
  const int d0 = blockIdx.x * 32, s0 = blockIdx.y * 32;
  const int tx = threadIdx.x, ty = threadIdx.y;
#pragma unroll
  for (int i = 0; i < 4; ++i)
    t[ty + i * 8][tx] = V[(long long)(s0 + ty + i * 8) * 1024 + d0 + tx];
  __syncthreads();
#pragma unroll
  for (int i = 0; i < 4; ++i)
    O[(long long)(d0 + ty + i * 8) * 2048 + s0 + tx] = t[tx][ty + i * 8];
}

extern "C" void kernel_launch(void* const* d_in, const int* in_sizes, int n_in,
                              void* d_out, int out_size, void* d_ws,
                              size_t ws_size, hipStream_t stream) {
  const float* x  = (const float*)d_in[0];
  const float* Wq = (const float*)d_in[1];
  const float* bq = (const float*)d_in[2];
  const float* Wk = (const float*)d_in[3];
  const float* bk = (const float*)d_in[4];
  const float* Wv = (const float*)d_in[5];
  const float* bv = (const float*)d_in[6];
  const float* Wt = (const float*)d_in[7];
  const float* bt = (const float*)d_in[8];
  const float* Wo = (const float*)d_in[9];
  const float* bo = (const float*)d_in[10];
  const float* es = (const float*)d_in[11];

  char* ws = (char*)d_ws;
  u16* WT   = (u16*)(ws);               // 5x [1024,1024] bf16 (WqT,WkT,WvT,WtT,WoT)
  u16* XB   = (u16*)(ws + 10485760);    // [8192,1024] bf16; later AV
  u16* Qcat = (u16*)(ws + 27262976);    // [8192,2048] bf16: Q/32 | es*r_q ; later ATT
  u16* Kcat = Qcat + 16777216;          // [8192,2048] bf16: K | r_k
  u16* Vb   = (u16*)(ws + 94371840);    // [8192,1024] bf16
  u16* VT   = (u16*)(ws + 111149056);   // [4][1024,2048] bf16
  u16* WtT  = WT + 3 * 1048576;
  u16* WoT  = WT + 4 * 1048576;
  u16* ATT  = Qcat;
  u16* AV   = XB;

  float* outO = (float*)d_out;          // [4,2048,1024]
  float* outA = outO + 8388608;         // [4,2048,2048]

  cvt_x<<<8192, 256, 0, stream>>>(x, XB);
  cvt_w<<<dim3(32, 32, 5), dim3(32, 8), 0, stream>>>(Wq, Wk, Wv, Wt, Wo, WT);
  // QKV projection (128x128 tiles, grid 1536)
  e3p<0><<<dim3(24, 64, 1), 256, 0, stream>>>(
      XB, 1024, 0, WT, 1024, 0, Qcat, Kcat, Vb, 0, 0, 1024, bq, bk, bv,
      1.f, nullptr);
  // theta (z=0: Q/32 -> es*r_q, ps=32; z=1: K -> r_k, ps=1), grid 1024
  e3p<1><<<dim3(8, 64, 2), 256, 0, stream>>>(
      Qcat, 2048, 16777216LL, WtT, 1024, 0, Qcat + 1024, nullptr, nullptr,
      2048, 16777216LL, 1024, bt, nullptr, nullptr, 32.f, es);
  transpose_v<<<dim3(32, 64, 4), dim3(32, 8), 0, stream>>>(Vb, VT);
  // logits = Qcat @ Kcat^T (K=2048), grid 1024
  e3p<4><<<dim3(16, 16, 4), 256, 0, stream>>>(
      Qcat, 2048, 4194304LL, Kcat, 2048, 4194304LL, outA, nullptr, nullptr,
      2048, 4194304LL, 2048, nullptr, nullptr, nullptr, 1.f, nullptr);
  softmax_rows<<<8192, 256, 0, stream>>>(outA, ATT);
  // attn @ V (grid 512)
  e3p<2><<<dim3(8, 16, 4), 256, 0, stream>>>(
      ATT, 2048, 4194304LL, VT, 2048, 2097152LL, AV, nullptr, nullptr,
      1024, 2097152LL, 2048, nullptr, nullptr, nullptr, 1.f, nullptr);
  // output projection (grid 512)
  e3p<3><<<dim3(8, 64, 1), 256, 0, stream>>>(
      AV, 1024, 0, WoT, 1024, 0, outO, nullptr, nullptr,
      1024, 0, 1024, bo, nullptr, nullptr, 1.f, nullptr);
}